// Round 12
// baseline (41.871 us; speedup 1.0000x reference)
//
#include <hip/hip_runtime.h>

#define NC 20
#define THREADS 256
#define BLOCKS 2048
#define GRAN 8             // int4 granules/thread: 2048*256*8 = 4,194,304 = n/4 exactly
#define EPSF 1e-10f

typedef unsigned long long u64;
typedef unsigned int u32;
typedef int v4i __attribute__((ext_vector_type(4)));

// ws layout: [0,240): u32 gc[60]; [256B on): part[30][BLOCKS]
#define PART_OFF 64        // in u32s
#define WS_NEEDED (256 + 30 * BLOCKS * 4)

// One-hot (3-bit fields, 20 classes in 60 bits) accumulate for one pair.
static __device__ __forceinline__ void pair_update(int p, int t,
                                                   u64& np, u64& nt, u64& ne)
{
    u64 ip = 1ull << (3 * p);
    u64 it = 1ull << (3 * t);
    np += ip;
    nt += it;
    ne += (p == t) ? ip : 0ull;   // branchless
}

// Stage 1 (UNCHANGED from round 11): forced 16-deep asm load burst + counted
// vmcnt drain + bit-sliced counting; per-block partials STORED (no atomics).
__global__ __launch_bounds__(THREADS) void dice_slice(
    const int* __restrict__ pred, const int* __restrict__ tgt,
    u32* __restrict__ part)
{
    constexpr u64 M = 0x01C71C71C71C71C7ull;  // 6-bit-spaced 3-bit mask (10 slots)
    __shared__ u32 swave[4][30];
    const int tid = threadIdx.x;
    const long long g = (long long)blockIdx.x * THREADS + tid;
    const u64 SB = (u64)BLOCKS * THREADS * 16ull;   // granule byte stride (8 MB)

    u64 baseP = (u64)pred + (u64)g * 16ull;
    u64 baseT = (u64)tgt  + (u64)g * 16ull;

    // ---- issue ALL 16 loads back-to-back; volatile asm cannot be reordered
    // or sunk by the compiler: 16 KB in flight per wave, guaranteed. ----
    v4i P[GRAN], T[GRAN];
    #pragma unroll
    for (int k = 0; k < GRAN; ++k) {
        asm volatile("global_load_dwordx4 %0, %2, off\n\t"
                     "global_load_dwordx4 %1, %3, off"
                     : "=&v"(P[k]), "=&v"(T[k])
                     : "v"(baseP + (u64)k * SB), "v"(baseT + (u64)k * SB));
    }

    // 6-bit-spaced accumulators, even classes in *e*, odd in *o*.
    // Per-class per-thread max = GRAN*4 = 32 <= 63: no overflow.
    u64 aeP=0, aoP=0, aeT=0, aoT=0, aeE=0, aoE=0;

    // Counted drain: granule K needs loads 2K,2K+1 -> wait vmcnt(14-2K).
    // "+v" ties order the compute after the wait via true data dependency.
    // Params K/W uppercase: lowercase w would capture the .w member token.
#define GRANULE(K, W)                                                          \
    do {                                                                       \
        asm volatile("s_waitcnt vmcnt(" #W ")" : "+v"(P[K]), "+v"(T[K]));      \
        u64 np = 0, nt = 0, ne = 0;   /* in-granule 3-bit fields (max 4) */    \
        pair_update(P[K].x, T[K].x, np, nt, ne);                               \
        pair_update(P[K].y, T[K].y, np, nt, ne);                               \
        pair_update(P[K].z, T[K].z, np, nt, ne);                               \
        pair_update(P[K].w, T[K].w, np, nt, ne);                               \
        aeP += np & M;        aoP += (np >> 3) & M;                            \
        aeT += nt & M;        aoT += (nt >> 3) & M;                            \
        aeE += ne & M;        aoE += (ne >> 3) & M;                            \
    } while (0)

    GRANULE(0, 14); GRANULE(1, 12); GRANULE(2, 10); GRANULE(3, 8);
    GRANULE(4, 6);  GRANULE(5, 4);  GRANULE(6, 2);  GRANULE(7, 0);
#undef GRANULE

    // Widen to u16-packed (class 2j | class 2j+1 << 16) and wave-reduce.
    // Wave sums per half <= 64*32 = 2048: no cross-carry.
    const int wid  = tid >> 6;
    const int lane = tid & 63;
    #pragma unroll
    for (int j = 0; j < 10; ++j) {
        const int sh = 6 * j;
        u32 sP = (u32)((aeP >> sh) & 63) | ((u32)((aoP >> sh) & 63) << 16);
        u32 sT = (u32)((aeT >> sh) & 63) | ((u32)((aoT >> sh) & 63) << 16);
        u32 sE = (u32)((aeE >> sh) & 63) | ((u32)((aoE >> sh) & 63) << 16);
        #pragma unroll
        for (int d = 32; d >= 1; d >>= 1) {
            sP += __shfl_down(sP, d, 64);
            sT += __shfl_down(sT, d, 64);
            sE += __shfl_down(sE, d, 64);
        }
        if (lane == 0) {
            swave[wid][j]      = sP;
            swave[wid][10 + j] = sT;
            swave[wid][20 + j] = sE;
        }
    }
    __syncthreads();

    // Block sums per half <= 4*2048 = 8192 (u16-safe). Plain store, own slot:
    // ZERO contended atomics anywhere in this kernel.
    if (tid < 30) {
        u32 s = swave[0][tid] + swave[1][tid] + swave[2][tid] + swave[3][tid];
        part[tid * BLOCKS + blockIdx.x] = s;
    }
}

// Stage 2 (PARALLEL, round-9 style): 30 blocks; block j sums its contiguous
// 8 KB partial row on its own CU -- avoids the single-CU 240 KB read whose
// ~7 B/cy service rate we suspect cost ~10 us in the fused version.
__global__ __launch_bounds__(THREADS) void dice_reduce(
    const u32* __restrict__ part, u32* __restrict__ gc)
{
    __shared__ u32 sw[2][4];
    const int j    = blockIdx.x;          // packed column 0..29
    const int tid  = threadIdx.x;
    const int wid  = tid >> 6;
    const int lane = tid & 63;
    u32 lo = 0, hi = 0;
    #pragma unroll
    for (int k = 0; k < BLOCKS / THREADS; ++k) {
        u32 v = part[j * BLOCKS + tid + k * THREADS];
        lo += v & 0xFFFFu;
        hi += v >> 16;
    }
    #pragma unroll
    for (int d = 32; d >= 1; d >>= 1) {
        lo += __shfl_down(lo, d, 64);
        hi += __shfl_down(hi, d, 64);
    }
    if (lane == 0) { sw[0][wid] = lo; sw[1][wid] = hi; }
    __syncthreads();
    if (tid == 0) {
        lo = sw[0][0] + sw[0][1] + sw[0][2] + sw[0][3];
        hi = sw[1][0] + sw[1][1] + sw[1][2] + sw[1][3];
        const int hist = j / 10;
        const int k2   = j % 10;
        gc[hist * NC + 2 * k2]     = lo;   // class 2k
        gc[hist * NC + 2 * k2 + 1] = hi;   // class 2k+1
    }
}

// Generic fallback (any n divisible by 4): joint-histogram kernel w/ atomics.
__global__ __launch_bounds__(THREADS) void dice_joint(
    const int* __restrict__ pred, const int* __restrict__ tgt,
    u32* __restrict__ gc, long long n4)
{
    __shared__ u32 h[4 * NC * NC];
    const int tid = threadIdx.x;
    for (int k = tid; k < 4 * NC * NC; k += THREADS) h[k] = 0u;
    __syncthreads();
    u32* hw = &h[(tid >> 6) * NC * NC];
    const int4* p4 = (const int4*)pred;
    const int4* t4 = (const int4*)tgt;
    const long long stride = (long long)2048 * THREADS;
    for (long long i = (long long)blockIdx.x * THREADS + tid; i < n4; i += stride) {
        int4 Pv = p4[i];
        int4 Tv = t4[i];
        atomicAdd(&hw[Pv.x * NC + Tv.x], 1u);
        atomicAdd(&hw[Pv.y * NC + Tv.y], 1u);
        atomicAdd(&hw[Pv.z * NC + Tv.z], 1u);
        atomicAdd(&hw[Pv.w * NC + Tv.w], 1u);
    }
    __syncthreads();
    for (int k = tid; k < NC * NC; k += THREADS)
        h[k] = h[k] + h[NC*NC + k] + h[2*NC*NC + k] + h[3*NC*NC + k];
    __syncthreads();
    if (tid < 3 * (NC - 1)) {
        const int which = tid / (NC - 1);
        const int c     = tid % (NC - 1) + 1;
        u32 s = 0;
        if (which == 0)      { for (int t = 0; t < NC; ++t) s += h[c * NC + t]; }
        else if (which == 1) { for (int p = 0; p < NC; ++p) s += h[p * NC + c]; }
        else                 { s = h[c * NC + c]; }
        atomicAdd(&gc[which * NC + c], s);
    }
}

__global__ void dice_final(const u32* __restrict__ gc, float* __restrict__ out)
{
    const int c = threadIdx.x;  // 64 lanes, classes 1..19 contribute
    float contrib = 0.0f;
    if (c >= 1 && c < NC) {
        float pc = (float)gc[c];
        float tc = (float)gc[NC + c];
        float tp = (float)gc[2 * NC + c];
        contrib = 2.0f * tp / (pc + tc + EPSF);
    }
    #pragma unroll
    for (int d = 32; d >= 1; d >>= 1) contrib += __shfl_down(contrib, d, 64);
    if (c == 0) out[0] = contrib * (1.0f / 19.0f);
}

extern "C" void kernel_launch(void* const* d_in, const int* in_sizes, int n_in,
                              void* d_out, int out_size, void* d_ws, size_t ws_size,
                              hipStream_t stream) {
    const int* pred = (const int*)d_in[0];
    const int* tgt  = (const int*)d_in[1];
    u32* gc   = (u32*)d_ws;
    u32* part = (u32*)d_ws + PART_OFF;

    const int n  = in_sizes[0];        // 16,777,216
    const int n4 = n >> 2;             // 4,194,304 == BLOCKS*THREADS*GRAN

    if (n4 == BLOCKS * THREADS * GRAN && ws_size >= (size_t)WS_NEEDED) {
        // Atomic-free path: partials and gc fully overwritten each call.
        dice_slice<<<BLOCKS, THREADS, 0, stream>>>(pred, tgt, part);
        dice_reduce<<<30, THREADS, 0, stream>>>(part, gc);
    } else {
        (void)hipMemsetAsync(d_ws, 0, 3 * NC * sizeof(u32), stream);
        dice_joint<<<2048, THREADS, 0, stream>>>(pred, tgt, gc, (long long)n4);
    }
    dice_final<<<1, 64, 0, stream>>>(gc, (float*)d_out);
}

// Round 13
// 37.566 us; speedup vs baseline: 1.1146x; 1.1146x over previous
//
#include <hip/hip_runtime.h>

#define NC 20
#define THREADS 256
#define BLOCKS 2048
#define GRAN 8             // int4 granules/thread: 2048*256*8 = 4,194,304 = n/4 exactly
#define EPSF 1e-10f

typedef unsigned long long u64;
typedef unsigned int u32;

// ws layout: [0,240): u32 gc[60] (fallback path); [256B on): part[30][BLOCKS]
#define PART_OFF 64        // in u32s
#define WS_NEEDED (256 + 30 * BLOCKS * 4)

// One-hot (3-bit fields, 20 classes in 60 bits) accumulate for one pair.
static __device__ __forceinline__ void pair_update(int p, int t,
                                                   u64& np, u64& nt, u64& ne)
{
    u64 ip = 1ull << (3 * p);
    u64 it = 1ull << (3 * t);
    np += ip;
    nt += it;
    ne += (p == t) ? ip : 0ull;   // branchless
}

// Stage 1 (R9 slice, verbatim — measured faster than the asm-burst variant):
// compiler-scheduled loads + bit-sliced counting; partials STORED (no atomics).
__global__ __launch_bounds__(THREADS) void dice_slice(
    const int* __restrict__ pred, const int* __restrict__ tgt,
    u32* __restrict__ part)
{
    constexpr u64 M = 0x01C71C71C71C71C7ull;  // 6-bit-spaced 3-bit mask (10 slots)
    __shared__ u32 swave[4][30];
    const int tid = threadIdx.x;
    const int g   = blockIdx.x * THREADS + tid;
    const int S   = BLOCKS * THREADS;
    const int4* p4 = (const int4*)pred;
    const int4* t4 = (const int4*)tgt;

    // 6-bit-spaced accumulators, even classes in *e*, odd in *o*.
    // Per-class per-thread max = GRAN*4 = 32 <= 63: no overflow.
    u64 aeP=0, aoP=0, aeT=0, aoT=0, aeE=0, aoE=0;

    #pragma unroll
    for (int k = 0; k < GRAN; ++k) {
        int4 P = p4[g + k * S];
        int4 T = t4[g + k * S];
        u64 np = 0, nt = 0, ne = 0;   // in-granule 3-bit fields (max 4 <= 7)
        pair_update(P.x, T.x, np, nt, ne);
        pair_update(P.y, T.y, np, nt, ne);
        pair_update(P.z, T.z, np, nt, ne);
        pair_update(P.w, T.w, np, nt, ne);
        aeP += np & M;        aoP += (np >> 3) & M;
        aeT += nt & M;        aoT += (nt >> 3) & M;
        aeE += ne & M;        aoE += (ne >> 3) & M;
    }

    // Widen to u16-packed (class 2j | class 2j+1 << 16) and wave-reduce.
    // Wave sums per half <= 64*32 = 2048: no cross-carry.
    const int wid  = tid >> 6;
    const int lane = tid & 63;
    #pragma unroll
    for (int j = 0; j < 10; ++j) {
        const int sh = 6 * j;
        u32 sP = (u32)((aeP >> sh) & 63) | ((u32)((aoP >> sh) & 63) << 16);
        u32 sT = (u32)((aeT >> sh) & 63) | ((u32)((aoT >> sh) & 63) << 16);
        u32 sE = (u32)((aeE >> sh) & 63) | ((u32)((aoE >> sh) & 63) << 16);
        #pragma unroll
        for (int d = 32; d >= 1; d >>= 1) {
            sP += __shfl_down(sP, d, 64);
            sT += __shfl_down(sT, d, 64);
            sE += __shfl_down(sE, d, 64);
        }
        if (lane == 0) {
            swave[wid][j]      = sP;
            swave[wid][10 + j] = sT;
            swave[wid][20 + j] = sE;
        }
    }
    __syncthreads();

    // Block sums per half <= 4*2048 = 8192 (u16-safe). Plain store, own slot:
    // ZERO contended atomics anywhere in this kernel.
    if (tid < 30) {
        u32 s = swave[0][tid] + swave[1][tid] + swave[2][tid] + swave[3][tid];
        part[tid * BLOCKS + blockIdx.x] = s;
    }
}

// Stage 2 (R11 fused reduce + finalize, verbatim — measured 4.9 us cheaper
// than separate reduce + final launches): 1 block, 1024 threads; half-wave
// per packed column, vectorized uint4 reads of the contiguous row.
__global__ __launch_bounds__(1024) void dice_reduce_final(
    const u32* __restrict__ part, float* __restrict__ out)
{
    __shared__ u32 cls[64];               // 60 counters (hist*20 + class)
    const int tid = threadIdx.x;
    const int j   = tid >> 5;             // packed column 0..31 (use <30)
    const int l   = tid & 31;
    if (j < 30) {
        const uint4* row = (const uint4*)(part + j * BLOCKS);
        u32 lo = 0, hi = 0;
        #pragma unroll
        for (int i = 0; i < BLOCKS / 128; ++i) {      // 16 x 16B per lane
            uint4 v = row[l + i * 32];
            lo += (v.x & 0xFFFFu) + (v.y & 0xFFFFu) + (v.z & 0xFFFFu) + (v.w & 0xFFFFu);
            hi += (v.x >> 16)     + (v.y >> 16)     + (v.z >> 16)     + (v.w >> 16);
        }
        #pragma unroll
        for (int d = 16; d >= 1; d >>= 1) {
            lo += __shfl_down(lo, d, 32);
            hi += __shfl_down(hi, d, 32);
        }
        if (l == 0) {
            const int hist = j / 10, kk = j % 10;
            cls[hist * NC + 2 * kk]     = lo;   // class 2k
            cls[hist * NC + 2 * kk + 1] = hi;   // class 2k+1
        }
    }
    __syncthreads();
    if (tid < 64) {
        const int c = tid;                // classes 1..19 contribute
        float contrib = 0.0f;
        if (c >= 1 && c < NC) {
            float pc = (float)cls[c];
            float tc = (float)cls[NC + c];
            float tp = (float)cls[2 * NC + c];
            contrib = 2.0f * tp / (pc + tc + EPSF);
        }
        #pragma unroll
        for (int d = 32; d >= 1; d >>= 1) contrib += __shfl_down(contrib, d, 64);
        if (tid == 0) out[0] = contrib * (1.0f / 19.0f);
    }
}

// Generic fallback (any n divisible by 4): joint-histogram kernel w/ atomics.
__global__ __launch_bounds__(THREADS) void dice_joint(
    const int* __restrict__ pred, const int* __restrict__ tgt,
    u32* __restrict__ gc, long long n4)
{
    __shared__ u32 h[4 * NC * NC];
    const int tid = threadIdx.x;
    for (int k = tid; k < 4 * NC * NC; k += THREADS) h[k] = 0u;
    __syncthreads();
    u32* hw = &h[(tid >> 6) * NC * NC];
    const int4* p4 = (const int4*)pred;
    const int4* t4 = (const int4*)tgt;
    const long long stride = (long long)2048 * THREADS;
    for (long long i = (long long)blockIdx.x * THREADS + tid; i < n4; i += stride) {
        int4 Pv = p4[i];
        int4 Tv = t4[i];
        atomicAdd(&hw[Pv.x * NC + Tv.x], 1u);
        atomicAdd(&hw[Pv.y * NC + Tv.y], 1u);
        atomicAdd(&hw[Pv.z * NC + Tv.z], 1u);
        atomicAdd(&hw[Pv.w * NC + Tv.w], 1u);
    }
    __syncthreads();
    for (int k = tid; k < NC * NC; k += THREADS)
        h[k] = h[k] + h[NC*NC + k] + h[2*NC*NC + k] + h[3*NC*NC + k];
    __syncthreads();
    if (tid < 3 * (NC - 1)) {
        const int which = tid / (NC - 1);
        const int c     = tid % (NC - 1) + 1;
        u32 s = 0;
        if (which == 0)      { for (int t = 0; t < NC; ++t) s += h[c * NC + t]; }
        else if (which == 1) { for (int p = 0; p < NC; ++p) s += h[p * NC + c]; }
        else                 { s = h[c * NC + c]; }
        atomicAdd(&gc[which * NC + c], s);
    }
}

__global__ void dice_final(const u32* __restrict__ gc, float* __restrict__ out)
{
    const int c = threadIdx.x;
    float contrib = 0.0f;
    if (c >= 1 && c < NC) {
        float pc = (float)gc[c];
        float tc = (float)gc[NC + c];
        float tp = (float)gc[2 * NC + c];
        contrib = 2.0f * tp / (pc + tc + EPSF);
    }
    #pragma unroll
    for (int d = 32; d >= 1; d >>= 1) contrib += __shfl_down(contrib, d, 64);
    if (c == 0) out[0] = contrib * (1.0f / 19.0f);
}

extern "C" void kernel_launch(void* const* d_in, const int* in_sizes, int n_in,
                              void* d_out, int out_size, void* d_ws, size_t ws_size,
                              hipStream_t stream) {
    const int* pred = (const int*)d_in[0];
    const int* tgt  = (const int*)d_in[1];
    u32* gc   = (u32*)d_ws;
    u32* part = (u32*)d_ws + PART_OFF;

    const int n  = in_sizes[0];        // 16,777,216
    const int n4 = n >> 2;             // 4,194,304 == BLOCKS*THREADS*GRAN

    if (n4 == BLOCKS * THREADS * GRAN && ws_size >= (size_t)WS_NEEDED) {
        // Atomic-free 2-launch path: partials fully overwritten each call.
        dice_slice<<<BLOCKS, THREADS, 0, stream>>>(pred, tgt, part);
        dice_reduce_final<<<1, 1024, 0, stream>>>(part, (float*)d_out);
    } else {
        (void)hipMemsetAsync(d_ws, 0, 3 * NC * sizeof(u32), stream);
        dice_joint<<<2048, THREADS, 0, stream>>>(pred, tgt, gc, (long long)n4);
        dice_final<<<1, 64, 0, stream>>>(gc, (float*)d_out);
    }
}

// Round 15
// 36.180 us; speedup vs baseline: 1.1573x; 1.0383x over previous
//
#include <hip/hip_runtime.h>

#define NC 20
#define THREADS 256
#define BLOCKS 2048
#define GRAN 8             // int4 granules/thread: 2048*256*8 = 4,194,304 = n/4 exactly
#define EPSF 1e-10f

typedef unsigned long long u64;
typedef unsigned int u32;
typedef int  v4i __attribute__((ext_vector_type(4)));   // nt-load-compatible
typedef u32  v4u __attribute__((ext_vector_type(4)));

// ws layout: [0,240): u32 gc[60] (fallback path); [256B on): part[30][BLOCKS]
#define PART_OFF 64        // in u32s
#define WS_NEEDED (256 + 30 * BLOCKS * 4)

// One-hot (3-bit fields, 20 classes in 60 bits) accumulate for one pair.
static __device__ __forceinline__ void pair_update(int p, int t,
                                                   u64& np, u64& nt, u64& ne)
{
    u64 ip = 1ull << (3 * p);
    u64 it = 1ull << (3 * t);
    np += ip;
    nt += it;
    ne += (p == t) ? ip : 0ull;   // branchless
}

// Stage 1: R13 slice with ONE change — non-temporal loads (skip L2
// allocation for the never-re-read stream). v4i ext-vector type because
// __builtin_nontemporal_load rejects HIP_vector_type structs.
__global__ __launch_bounds__(THREADS) void dice_slice(
    const int* __restrict__ pred, const int* __restrict__ tgt,
    u32* __restrict__ part)
{
    constexpr u64 M = 0x01C71C71C71C71C7ull;  // 6-bit-spaced 3-bit mask (10 slots)
    __shared__ u32 swave[4][30];
    const int tid = threadIdx.x;
    const int g   = blockIdx.x * THREADS + tid;
    const int S   = BLOCKS * THREADS;
    const v4i* p4 = (const v4i*)pred;
    const v4i* t4 = (const v4i*)tgt;

    // 6-bit-spaced accumulators, even classes in *e*, odd in *o*.
    // Per-class per-thread max = GRAN*4 = 32 <= 63: no overflow.
    u64 aeP=0, aoP=0, aeT=0, aoT=0, aeE=0, aoE=0;

    #pragma unroll
    for (int k = 0; k < GRAN; ++k) {
        v4i P = __builtin_nontemporal_load(&p4[g + k * S]);
        v4i T = __builtin_nontemporal_load(&t4[g + k * S]);
        u64 np = 0, nt = 0, ne = 0;   // in-granule 3-bit fields (max 4 <= 7)
        pair_update(P.x, T.x, np, nt, ne);
        pair_update(P.y, T.y, np, nt, ne);
        pair_update(P.z, T.z, np, nt, ne);
        pair_update(P.w, T.w, np, nt, ne);
        aeP += np & M;        aoP += (np >> 3) & M;
        aeT += nt & M;        aoT += (nt >> 3) & M;
        aeE += ne & M;        aoE += (ne >> 3) & M;
    }

    // Widen to u16-packed (class 2j | class 2j+1 << 16) and wave-reduce.
    // Wave sums per half <= 64*32 = 2048: no cross-carry.
    const int wid  = tid >> 6;
    const int lane = tid & 63;
    #pragma unroll
    for (int j = 0; j < 10; ++j) {
        const int sh = 6 * j;
        u32 sP = (u32)((aeP >> sh) & 63) | ((u32)((aoP >> sh) & 63) << 16);
        u32 sT = (u32)((aeT >> sh) & 63) | ((u32)((aoT >> sh) & 63) << 16);
        u32 sE = (u32)((aeE >> sh) & 63) | ((u32)((aoE >> sh) & 63) << 16);
        #pragma unroll
        for (int d = 32; d >= 1; d >>= 1) {
            sP += __shfl_down(sP, d, 64);
            sT += __shfl_down(sT, d, 64);
            sE += __shfl_down(sE, d, 64);
        }
        if (lane == 0) {
            swave[wid][j]      = sP;
            swave[wid][10 + j] = sT;
            swave[wid][20 + j] = sE;
        }
    }
    __syncthreads();

    // Block sums per half <= 4*2048 = 8192 (u16-safe). Plain store, own slot:
    // ZERO contended atomics anywhere in this kernel.
    if (tid < 30) {
        u32 s = swave[0][tid] + swave[1][tid] + swave[2][tid] + swave[3][tid];
        part[tid * BLOCKS + blockIdx.x] = s;
    }
}

// Stage 2 (fused reduce + finalize): 1 block, 1024 threads; half-wave per
// packed column, vectorized non-temporal v4u reads of the contiguous row.
__global__ __launch_bounds__(1024) void dice_reduce_final(
    const u32* __restrict__ part, float* __restrict__ out)
{
    __shared__ u32 cls[64];               // 60 counters (hist*20 + class)
    const int tid = threadIdx.x;
    const int j   = tid >> 5;             // packed column 0..31 (use <30)
    const int l   = tid & 31;
    if (j < 30) {
        const v4u* row = (const v4u*)(part + j * BLOCKS);
        u32 lo = 0, hi = 0;
        #pragma unroll
        for (int i = 0; i < BLOCKS / 128; ++i) {      // 16 x 16B per lane
            v4u v = __builtin_nontemporal_load(&row[l + i * 32]);
            lo += (v.x & 0xFFFFu) + (v.y & 0xFFFFu) + (v.z & 0xFFFFu) + (v.w & 0xFFFFu);
            hi += (v.x >> 16)     + (v.y >> 16)     + (v.z >> 16)     + (v.w >> 16);
        }
        #pragma unroll
        for (int d = 16; d >= 1; d >>= 1) {
            lo += __shfl_down(lo, d, 32);
            hi += __shfl_down(hi, d, 32);
        }
        if (l == 0) {
            const int hist = j / 10, kk = j % 10;
            cls[hist * NC + 2 * kk]     = lo;   // class 2k
            cls[hist * NC + 2 * kk + 1] = hi;   // class 2k+1
        }
    }
    __syncthreads();
    if (tid < 64) {
        const int c = tid;                // classes 1..19 contribute
        float contrib = 0.0f;
        if (c >= 1 && c < NC) {
            float pc = (float)cls[c];
            float tc = (float)cls[NC + c];
            float tp = (float)cls[2 * NC + c];
            contrib = 2.0f * tp / (pc + tc + EPSF);
        }
        #pragma unroll
        for (int d = 32; d >= 1; d >>= 1) contrib += __shfl_down(contrib, d, 64);
        if (tid == 0) out[0] = contrib * (1.0f / 19.0f);
    }
}

// Generic fallback (any n divisible by 4): joint-histogram kernel w/ atomics.
__global__ __launch_bounds__(THREADS) void dice_joint(
    const int* __restrict__ pred, const int* __restrict__ tgt,
    u32* __restrict__ gc, long long n4)
{
    __shared__ u32 h[4 * NC * NC];
    const int tid = threadIdx.x;
    for (int k = tid; k < 4 * NC * NC; k += THREADS) h[k] = 0u;
    __syncthreads();
    u32* hw = &h[(tid >> 6) * NC * NC];
    const int4* p4 = (const int4*)pred;
    const int4* t4 = (const int4*)tgt;
    const long long stride = (long long)2048 * THREADS;
    for (long long i = (long long)blockIdx.x * THREADS + tid; i < n4; i += stride) {
        int4 Pv = p4[i];
        int4 Tv = t4[i];
        atomicAdd(&hw[Pv.x * NC + Tv.x], 1u);
        atomicAdd(&hw[Pv.y * NC + Tv.y], 1u);
        atomicAdd(&hw[Pv.z * NC + Tv.z], 1u);
        atomicAdd(&hw[Pv.w * NC + Tv.w], 1u);
    }
    __syncthreads();
    for (int k = tid; k < NC * NC; k += THREADS)
        h[k] = h[k] + h[NC*NC + k] + h[2*NC*NC + k] + h[3*NC*NC + k];
    __syncthreads();
    if (tid < 3 * (NC - 1)) {
        const int which = tid / (NC - 1);
        const int c     = tid % (NC - 1) + 1;
        u32 s = 0;
        if (which == 0)      { for (int t = 0; t < NC; ++t) s += h[c * NC + t]; }
        else if (which == 1) { for (int p = 0; p < NC; ++p) s += h[p * NC + c]; }
        else                 { s = h[c * NC + c]; }
        atomicAdd(&gc[which * NC + c], s);
    }
}

__global__ void dice_final(const u32* __restrict__ gc, float* __restrict__ out)
{
    const int c = threadIdx.x;
    float contrib = 0.0f;
    if (c >= 1 && c < NC) {
        float pc = (float)gc[c];
        float tc = (float)gc[NC + c];
        float tp = (float)gc[2 * NC + c];
        contrib = 2.0f * tp / (pc + tc + EPSF);
    }
    #pragma unroll
    for (int d = 32; d >= 1; d >>= 1) contrib += __shfl_down(contrib, d, 64);
    if (c == 0) out[0] = contrib * (1.0f / 19.0f);
}

extern "C" void kernel_launch(void* const* d_in, const int* in_sizes, int n_in,
                              void* d_out, int out_size, void* d_ws, size_t ws_size,
                              hipStream_t stream) {
    const int* pred = (const int*)d_in[0];
    const int* tgt  = (const int*)d_in[1];
    u32* gc   = (u32*)d_ws;
    u32* part = (u32*)d_ws + PART_OFF;

    const int n  = in_sizes[0];        // 16,777,216
    const int n4 = n >> 2;             // 4,194,304 == BLOCKS*THREADS*GRAN

    if (n4 == BLOCKS * THREADS * GRAN && ws_size >= (size_t)WS_NEEDED) {
        // Atomic-free 2-launch path: partials fully overwritten each call.
        dice_slice<<<BLOCKS, THREADS, 0, stream>>>(pred, tgt, part);
        dice_reduce_final<<<1, 1024, 0, stream>>>(part, (float*)d_out);
    } else {
        (void)hipMemsetAsync(d_ws, 0, 3 * NC * sizeof(u32), stream);
        dice_joint<<<2048, THREADS, 0, stream>>>(pred, tgt, gc, (long long)n4);
        dice_final<<<1, 64, 0, stream>>>(gc, (float*)d_out);
    }
}